// Round 9
// baseline (545.300 us; speedup 1.0000x reference)
//
#include <hip/hip_runtime.h>
#include <hip/hip_bf16.h>
#include <math.h>

typedef __bf16 bf16x8 __attribute__((ext_vector_type(8)));
typedef __bf16 bf16x4 __attribute__((ext_vector_type(4)));
typedef float f32x4 __attribute__((ext_vector_type(4)));

typedef __attribute__((address_space(3))) unsigned int lds_u32_t;
typedef __attribute__((address_space(1))) const unsigned int glb_u32_t;

static __device__ __forceinline__ f32x4 mfma16(bf16x8 a, bf16x8 b, f32x4 c) {
  return __builtin_amdgcn_mfma_f32_16x16x32_bf16(a, b, c, 0, 0, 0);
}

static __device__ __forceinline__ float fast_exp2(float x) {
#if __has_builtin(__builtin_amdgcn_exp2f)
  return __builtin_amdgcn_exp2f(x);
#else
  return exp2f(x);
#endif
}

static __device__ __forceinline__ float fast_rcp(float x) {
#if __has_builtin(__builtin_amdgcn_rcpf)
  return __builtin_amdgcn_rcpf(x);
#else
  return 1.f / x;
#endif
}

// GELU with A&S 7.1.26 erf (max abs err 1.5e-7 — far below bf16 quantum).
// Replaces libm erff: ~40us of VALU per F1 dispatch at 128 evals/thread.
static __device__ __forceinline__ float fast_gelu(float x) {
  float z = x * 0.70710678118654752f;
  float az = fabsf(z);
  float t = fast_rcp(fmaf(0.3275911f, az, 1.f));
  float poly = t * fmaf(t, fmaf(t, fmaf(t, fmaf(t, 1.061405429f, -1.453152027f),
                                        1.421413741f), -0.284496736f), 0.254829592f);
  float e = fast_exp2(-az * az * 1.4426950408889634f);
  float erf_abs = fmaf(-poly, e, 1.f);
  float erfv = copysignf(erf_abs, z);
  return 0.5f * x * (1.f + erfv);
}

static __device__ __forceinline__ void load_lds16(const __bf16* g, __bf16* l) {
  __builtin_amdgcn_global_load_lds((glb_u32_t*)g, (lds_u32_t*)l, 16, 0, 0);
}

// ---------------- weight transpose: src[R][C] fp32 -> dst[C][R] bf16 ----------------
__global__ __launch_bounds__(256) void transpose_w(const float* __restrict__ src,
                                                   __bf16* __restrict__ dst,
                                                   int R, int C) {
  __shared__ float tile[32][33];
  int tx = threadIdx.x, ty = threadIdx.y;
  int c0 = blockIdx.x * 32, r0 = blockIdx.y * 32;
#pragma unroll
  for (int i = 0; i < 4; i++)
    tile[ty + 8 * i][tx] = src[(size_t)(r0 + ty + 8 * i) * C + c0 + tx];
  __syncthreads();
#pragma unroll
  for (int i = 0; i < 4; i++)
    dst[(size_t)(c0 + ty + 8 * i) * R + r0 + tx] = (__bf16)tile[tx][ty + 8 * i];
}

// ---------------- layernorm (row=1024) fp32 in -> bf16 out ----------------
__global__ __launch_bounds__(256) void ln_kernel(const float* __restrict__ x,
                                                 const float* __restrict__ w,
                                                 const float* __restrict__ b,
                                                 __bf16* __restrict__ out) {
  int row = blockIdx.x, tid = threadIdx.x;
  const float* xr = x + (size_t)row * 1024;
  float v[4];
  float s = 0.f, sq = 0.f;
#pragma unroll
  for (int i = 0; i < 4; i++) {
    v[i] = xr[tid + 256 * i];
    s += v[i];
    sq += v[i] * v[i];
  }
#pragma unroll
  for (int off = 1; off < 64; off <<= 1) {
    s += __shfl_xor(s, off, 64);
    sq += __shfl_xor(sq, off, 64);
  }
  __shared__ float red[8];
  int wave = tid >> 6, lane = tid & 63;
  if (lane == 0) { red[wave] = s; red[4 + wave] = sq; }
  __syncthreads();
  if (tid == 0) {
    float S = red[0] + red[1] + red[2] + red[3];
    float SQ = red[4] + red[5] + red[6] + red[7];
    float mu = S * (1.f / 1024.f);
    float var = SQ * (1.f / 1024.f) - mu * mu;
    red[0] = mu;
    red[1] = rsqrtf(var + 1e-5f);
  }
  __syncthreads();
  float mu = red[0], rstd = red[1];
  __bf16* orow = out + (size_t)row * 1024;
#pragma unroll
  for (int i = 0; i < 4; i++) {
    int c = tid + 256 * i;
    orow[c] = (__bf16)((v[i] - mu) * rstd * w[c] + b[c]);
  }
}

// ---------------- GEMM modes ----------------
enum { MODE_QKV = 0, MODE_WO = 3, MODE_F1 = 4, MODE_F2 = 5 };

// ---------------- 128x128 GEMM (m97-structure) — kept for WO / F2 ----------------
template <int MODE>
__global__ __launch_bounds__(256, 2) void gemm_bt(const __bf16* __restrict__ A,
                                                  const __bf16* __restrict__ Bt,
                                                  const float* __restrict__ b0,
                                                  const float* __restrict__ b1,
                                                  const float* __restrict__ b2,
                                                  const float* __restrict__ aux,
                                                  void* __restrict__ o0,
                                                  void* __restrict__ o1,
                                                  void* __restrict__ o2,
                                                  int N, int K) {
  __shared__ __align__(16) __bf16 As[128 * 64];
  __shared__ __align__(16) __bf16 Bs[128 * 64];
  const int tid = threadIdx.x;
  const int m0 = blockIdx.y * 128, n0 = blockIdx.x * 128;
  const int wave = tid >> 6, lane = tid & 63, quad = lane >> 4, l16 = lane & 15;
  const int wm = (wave >> 1) * 64, wn = (wave & 1) * 64;

  int srow[4], sgran[4];
#pragma unroll
  for (int i = 0; i < 4; i++) {
    int inst = wave * 4 + i;
    srow[i] = inst * 8 + (lane >> 3);
    sgran[i] = (lane & 7) ^ (srow[i] & 7);
  }

  const f32x4 zero4 = {0.f, 0.f, 0.f, 0.f};
  f32x4 acc[4][4];
#pragma unroll
  for (int i = 0; i < 4; i++)
#pragma unroll
    for (int j = 0; j < 4; j++) acc[i][j] = zero4;

  for (int kt = 0; kt < K; kt += 64) {
#pragma unroll
    for (int i = 0; i < 4; i++) {
      int inst = wave * 4 + i;
      load_lds16(&A[(size_t)(m0 + srow[i]) * K + kt + sgran[i] * 8], &As[inst * 512]);
      load_lds16(&Bt[(size_t)(n0 + srow[i]) * K + kt + sgran[i] * 8], &Bs[inst * 512]);
    }
    __syncthreads();
#pragma unroll
    for (int ks = 0; ks < 64; ks += 32) {
      bf16x8 af[4], bfv[4];
#pragma unroll
      for (int mi = 0; mi < 4; mi++) {
        int row = wm + 16 * mi + l16;
        int pg = ((ks >> 3) + quad) ^ (row & 7);
        af[mi] = *(const bf16x8*)&As[row * 64 + pg * 8];
      }
#pragma unroll
      for (int ni = 0; ni < 4; ni++) {
        int row = wn + 16 * ni + l16;
        int pg = ((ks >> 3) + quad) ^ (row & 7);
        bfv[ni] = *(const bf16x8*)&Bs[row * 64 + pg * 8];
      }
#pragma unroll
      for (int mi = 0; mi < 4; mi++)
#pragma unroll
        for (int ni = 0; ni < 4; ni++)
          acc[mi][ni] = mfma16(af[mi], bfv[ni], acc[mi][ni]);
    }
    __syncthreads();
  }

  int seg = (n0 >> 10);
  const float* bsel = (MODE == MODE_QKV) ? (seg == 0 ? b0 : seg == 1 ? b1 : b2) : b0;

#pragma unroll
  for (int mi = 0; mi < 4; mi++) {
#pragma unroll
    for (int ni = 0; ni < 4; ni++) {
      int ncol = n0 + wn + 16 * ni + l16;
      int cc = ncol & 1023;
      float bval = bsel[(MODE == MODE_QKV) ? cc : ncol];
#pragma unroll
      for (int r = 0; r < 4; r++) {
        int m = m0 + wm + 16 * mi + quad * 4 + r;
        float val = acc[mi][ni][r] + bval;
        if constexpr (MODE == MODE_QKV) {
          int bb = m >> 10, s = m & 1023, h = cc >> 6, dk = cc & 63;
          if (seg == 0)
            ((__bf16*)o0)[(((size_t)(bb * 16 + h)) * 1024 + s) * 64 + dk] =
                (__bf16)(val * 0.18033688011112042f);
          else if (seg == 1)
            ((__bf16*)o1)[(((size_t)(bb * 16 + h)) * 1024 + s) * 64 + dk] = (__bf16)val;
          else
            ((__bf16*)o2)[(((size_t)(bb * 16 + h)) * 64 + dk) * 1024 + s] = (__bf16)val;
        } else if constexpr (MODE == MODE_WO) {
          val = fmaxf(val, 0.f);
          size_t idx = (size_t)m * 1024 + ncol;
          ((float*)o0)[idx] = aux[idx] + val;
        } else if constexpr (MODE == MODE_F1) {
          ((__bf16*)o0)[(size_t)m * 4096 + ncol] = (__bf16)fast_gelu(val);
        } else {
          size_t idx = (size_t)m * 1024 + ncol;
          ((float*)o0)[idx] = aux[idx] + val;
        }
      }
    }
  }
}

// ---------------- 256x256 GEMM v2: [k-octet][row] LDS panels, ring-4, counted vmcnt
// R7 counters (F1): MfmaUtil 27%, VALU 44%, BANK_CONFLICT 6.29M = +4cy per
// ds_read_b128 — the pair-interleave XOR swizzle gave fixed 8-lane groups duplicate
// granule slots ({0,1,1,0,...}) -> 2-way conflicts. v2 layout: slot byte =
// g*4096 + r*16 (g = k-octet 0..3, r = tile row 0..255). Fragment read (panel=quad):
// lanes of a quad hit 16 consecutive rows = 256B contiguous; any 8 consecutive
// lanes cover 8 distinct granules = all 32 banks -> ZERO conflicts, no swizzle.
// Staging keeps global_load_lds linear dst: per issue g, lane = row (stride-K src);
// the 4 g-issues of one row-set share a 64B line (L1/TCP reuse) so no over-fetch.
// Waves 0-3 stage A, waves 4-7 stage B; still 4 issues/wave/stage, so the
// vmcnt(8)/(4)/(0) bookkeeping is unchanged from the R7-verified ring.
template <int MODE>
__global__ __launch_bounds__(512, 2) void gemm256(const __bf16* __restrict__ A,
                                                  const __bf16* __restrict__ Bt,
                                                  const float* __restrict__ b0,
                                                  const float* __restrict__ b1,
                                                  const float* __restrict__ b2,
                                                  const float* __restrict__ aux,
                                                  void* __restrict__ o0,
                                                  void* __restrict__ o1,
                                                  void* __restrict__ o2,
                                                  int N, int K) {
  __shared__ __align__(16) __bf16 As[4][8192];  // slot: [g 0..3][row 0..255] 16B granules
  __shared__ __align__(16) __bf16 Bs[4][8192];
  const int tid = threadIdx.x;
  const int m0 = blockIdx.y * 256, n0 = blockIdx.x * 256;
  const int wave = tid >> 6, lane = tid & 63, quad = lane >> 4, l16 = lane & 15;
  const int wr = wave >> 2, wc = wave & 3;  // 2 x 4 wave grid; per-wave 128 x 64 output

  // staging: this wave's source row pointer (lane = row within its 64-row chunk)
  const __bf16* pS = (wave < 4)
                         ? A + (size_t)(m0 + wave * 64 + lane) * K
                         : Bt + (size_t)(n0 + (wave - 4) * 64 + lane) * K;
  const int dstoff = (wave & 3) * 512;  // elements: rows (wave&3)*64.., 16B each

  // fragment read offsets (bytes): granule=quad panel + row*16
  const int aoff = quad * 4096 + (wr * 128 + l16) * 16;
  const int boff = quad * 4096 + (wc * 64 + l16) * 16;

  const f32x4 zero4 = {0.f, 0.f, 0.f, 0.f};
  f32x4 acc[8][4];
#pragma unroll
  for (int i = 0; i < 8; i++)
#pragma unroll
    for (int j = 0; j < 4; j++) acc[i][j] = zero4;

  const int nt = K >> 5;

  auto stage = [&](int t) {
    __bf16* b = ((wave < 4) ? &As[t & 3][0] : &Bs[t & 3][0]) + dstoff;
#pragma unroll
    for (int g = 0; g < 4; g++) load_lds16(pS + 8 * g, b + 2048 * g);
    pS += 32;
  };

  auto window = [&](int t, bool dostage) {
    const char* ab = (const char*)&As[t & 3][0];
    const char* bb = (const char*)&Bs[t & 3][0];
    bf16x8 af[8], bfv[4];
#pragma unroll
    for (int mi = 0; mi < 8; mi++) af[mi] = *(const bf16x8*)(ab + aoff + mi * 256);
#pragma unroll
    for (int nj = 0; nj < 4; nj++) bfv[nj] = *(const bf16x8*)(bb + boff + nj * 256);
    if (dostage) stage(t + 3);
    __builtin_amdgcn_s_setprio(1);
#pragma unroll
    for (int mi = 0; mi < 8; mi++)
#pragma unroll
      for (int nj = 0; nj < 4; nj++)
        acc[mi][nj] = mfma16(af[mi], bfv[nj], acc[mi][nj]);
    __builtin_amdgcn_s_setprio(0);
  };

  // prologue: 3 tiles in flight, wait for tile 0 only
  stage(0);
  stage(1);
  stage(2);
  asm volatile("s_waitcnt vmcnt(8)" ::: "memory");
  __builtin_amdgcn_s_barrier();
  __builtin_amdgcn_sched_barrier(0);

  for (int t = 0; t < nt - 3; ++t) {
    window(t, true);
    asm volatile("s_waitcnt vmcnt(8)" ::: "memory");
    __builtin_amdgcn_s_barrier();
    __builtin_amdgcn_sched_barrier(0);
  }
  window(nt - 3, false);
  asm volatile("s_waitcnt vmcnt(4)" ::: "memory");
  __builtin_amdgcn_s_barrier();
  __builtin_amdgcn_sched_barrier(0);
  window(nt - 2, false);
  asm volatile("s_waitcnt vmcnt(0)" ::: "memory");
  __builtin_amdgcn_s_barrier();
  __builtin_amdgcn_sched_barrier(0);
  window(nt - 1, false);

  // ---- epilogue (frag layout: col=l16, row=4*quad+r)
  int seg = (n0 >> 10);
  const float* bsel = (MODE == MODE_QKV) ? (seg == 0 ? b0 : seg == 1 ? b1 : b2) : b0;

#pragma unroll
  for (int mi = 0; mi < 8; mi++) {
#pragma unroll
    for (int nj = 0; nj < 4; nj++) {
      int ncol = n0 + wc * 64 + 16 * nj + l16;
      int cc = ncol & 1023;
      float bval = bsel[(MODE == MODE_QKV) ? cc : ncol];
#pragma unroll
      for (int r = 0; r < 4; r++) {
        int m = m0 + wr * 128 + 16 * mi + quad * 4 + r;
        float val = acc[mi][nj][r] + bval;
        if constexpr (MODE == MODE_QKV) {
          int bb = m >> 10, s = m & 1023, h = cc >> 6, dk = cc & 63;
          if (seg == 0)  // fold 1/sqrt(64) * log2(e) so attn uses raw exp2
            ((__bf16*)o0)[(((size_t)(bb * 16 + h)) * 1024 + s) * 64 + dk] =
                (__bf16)(val * 0.18033688011112042f);
          else if (seg == 1)
            ((__bf16*)o1)[(((size_t)(bb * 16 + h)) * 1024 + s) * 64 + dk] = (__bf16)val;
          else
            ((__bf16*)o2)[(((size_t)(bb * 16 + h)) * 64 + dk) * 1024 + s] = (__bf16)val;
        } else if constexpr (MODE == MODE_WO) {
          val = fmaxf(val, 0.f);
          size_t idx = (size_t)m * 1024 + ncol;
          ((float*)o0)[idx] = aux[idx] + val;
        } else if constexpr (MODE == MODE_F1) {
          ((__bf16*)o0)[(size_t)m * 4096 + ncol] = (__bf16)fast_gelu(val);
        } else {
          size_t idx = (size_t)m * 1024 + ncol;
          ((float*)o0)[idx] = aux[idx] + val;
        }
      }
    }
  }
}

// ---------------- flash attention v7: LDS-shared K/V tiles (unchanged, verified R7)
__global__ __launch_bounds__(256, 2) void attn_kernel(const __bf16* __restrict__ Q,
                                                      const __bf16* __restrict__ Kp,
                                                      const __bf16* __restrict__ Vt,
                                                      __bf16* __restrict__ ctx) {
  __shared__ __align__(16) __bf16 Ks[2][64][64];
  __shared__ __align__(16) __bf16 Vs[2][64][64];
  __shared__ __align__(16) __bf16 Ps[2][4][32][72];
  const int tid = threadIdx.x;
  const int bh = blockIdx.x, qb = blockIdx.y;
  const int wave = tid >> 6, lane = tid & 63, quad = lane >> 4, l16 = lane & 15;
  const int qrow0 = qb * 128 + wave * 32;

  bf16x8 aq[2][2];
#pragma unroll
  for (int mi = 0; mi < 2; mi++) {
    const __bf16* qrow = Q + ((size_t)bh * 1024 + qrow0 + mi * 16 + l16) * 64;
    aq[mi][0] = *(const bf16x8*)&qrow[8 * quad];
    aq[mi][1] = *(const bf16x8*)&qrow[32 + 8 * quad];
  }

  const f32x4 zero4 = {0.f, 0.f, 0.f, 0.f};
  f32x4 o[2][4];
  float lp[2] = {0.f, 0.f};
#pragma unroll
  for (int mi = 0; mi < 2; mi++)
#pragma unroll
    for (int nj = 0; nj < 4; nj++) o[mi][nj] = zero4;

  const __bf16* kb0 = Kp + (size_t)bh * 65536;
  const __bf16* vb0 = Vt + (size_t)bh * 65536;

  const int srow = lane >> 3;
  const int sgran = (lane & 7) ^ srow;
  const int r0 = wave * 16;

  auto stage = [&](int t) {
    int buf = t & 1;
    const __bf16* ks = kb0 + (size_t)(t * 64 + r0 + srow) * 64 + sgran * 8;
    load_lds16(ks, &Ks[buf][r0][0]);
    load_lds16(ks + 8 * 64, &Ks[buf][r0 + 8][0]);
    const __bf16* vs = vb0 + (size_t)(r0 + srow) * 1024 + t * 64 + sgran * 8;
    load_lds16(vs, &Vs[buf][r0][0]);
    load_lds16(vs + 8 * 1024, &Vs[buf][r0 + 8][0]);
  };

  int kOff[4][2], vOff[4][2];
#pragma unroll
  for (int ni = 0; ni < 4; ni++) {
    int r = 16 * ni + l16;
#pragma unroll
    for (int half = 0; half < 2; half++) {
      int g = quad + 4 * half;
      kOff[ni][half] = r * 128 + ((g ^ (r & 7)) * 16);
      vOff[ni][half] = kOff[ni][half];
    }
  }

  stage(0);
  asm volatile("s_waitcnt vmcnt(0)" ::: "memory");
  __builtin_amdgcn_s_barrier();

  for (int t = 0; t < 16; ++t) {
    const int buf = t & 1;
    if (t < 15) stage(t + 1);
    const char* kbuf_ = (const char*)&Ks[buf][0][0];
    const char* vbuf_ = (const char*)&Vs[buf][0][0];
    bf16x8 kf[4][2];
#pragma unroll
    for (int ni = 0; ni < 4; ni++) {
      kf[ni][0] = *(const bf16x8*)(kbuf_ + kOff[ni][0]);
      kf[ni][1] = *(const bf16x8*)(kbuf_ + kOff[ni][1]);
    }
    f32x4 st[2][4];
    __builtin_amdgcn_s_setprio(1);
#pragma unroll
    for (int mi = 0; mi < 2; mi++)
#pragma unroll
      for (int ni = 0; ni < 4; ni++) {
        st[mi][ni] = mfma16(kf[ni][0], aq[mi][0], zero4);
        st[mi][ni] = mfma16(kf[ni][1], aq[mi][1], st[mi][ni]);
      }
    __builtin_amdgcn_s_setprio(0);
    bf16x8 vf[2][4];
#pragma unroll
    for (int nj = 0; nj < 4; nj++) {
      vf[0][nj] = *(const bf16x8*)(vbuf_ + vOff[nj][0]);
      vf[1][nj] = *(const bf16x8*)(vbuf_ + vOff[nj][1]);
    }
#pragma unroll
    for (int mi = 0; mi < 2; mi++)
#pragma unroll
      for (int ni = 0; ni < 4; ni++) {
        union { bf16x4 v4; __bf16 b[4]; } pk;
#pragma unroll
        for (int r = 0; r < 4; r++) {
          float p = fast_exp2(st[mi][ni][r]);
          lp[mi] += p;
          pk.b[r] = (__bf16)p;
        }
        *(bf16x4*)&Ps[buf][wave][16 * mi + l16][16 * ni + 4 * quad] = pk.v4;
      }
    bf16x8 pa[2][2];
#pragma unroll
    for (int mi = 0; mi < 2; mi++) {
      pa[mi][0] = *(const bf16x8*)&Ps[buf][wave][16 * mi + l16][8 * quad];
      pa[mi][1] = *(const bf16x8*)&Ps[buf][wave][16 * mi + l16][32 + 8 * quad];
    }
    __builtin_amdgcn_s_setprio(1);
#pragma unroll
    for (int mi = 0; mi < 2; mi++)
#pragma unroll
      for (int nj = 0; nj < 4; nj++) {
        o[mi][nj] = mfma16(pa[mi][0], vf[0][nj], o[mi][nj]);
        o[mi][nj] = mfma16(pa[mi][1], vf[1][nj], o[mi][nj]);
      }
    __builtin_amdgcn_s_setprio(0);
    if (t < 15) {
      asm volatile("s_waitcnt vmcnt(0)" ::: "memory");
      __builtin_amdgcn_s_barrier();
    }
  }

#pragma unroll
  for (int mi = 0; mi < 2; mi++) {
    lp[mi] += __shfl_xor(lp[mi], 16, 64);
    lp[mi] += __shfl_xor(lp[mi], 32, 64);
  }

  int bb = bh >> 4, h = bh & 15;
#pragma unroll
  for (int mi = 0; mi < 2; mi++)
#pragma unroll
    for (int r = 0; r < 4; r++) {
      float inv = 1.f / __shfl(lp[mi], 4 * quad + r, 64);
      int s = qrow0 + mi * 16 + 4 * quad + r;
#pragma unroll
      for (int nj = 0; nj < 4; nj++)
        ctx[((size_t)(bb * 1024 + s)) * 1024 + h * 64 + nj * 16 + l16] =
            (__bf16)(o[mi][nj][r] * inv);
    }
}

// ---------------- launch ----------------
extern "C" void kernel_launch(void* const* d_in, const int* in_sizes, int n_in,
                              void* d_out, int out_size, void* d_ws, size_t ws_size,
                              hipStream_t stream) {
  const float* x = (const float*)d_in[0];
  const float* ln1w = (const float*)d_in[1];
  const float* ln1b = (const float*)d_in[2];
  const float* wq = (const float*)d_in[3];
  const float* bq = (const float*)d_in[4];
  const float* wk = (const float*)d_in[5];
  const float* bk = (const float*)d_in[6];
  const float* wv = (const float*)d_in[7];
  const float* bv = (const float*)d_in[8];
  const float* wo = (const float*)d_in[9];
  const float* bo = (const float*)d_in[10];
  const float* ln2w = (const float*)d_in[11];
  const float* ln2b = (const float*)d_in[12];
  const float* w1 = (const float*)d_in[13];
  const float* b1 = (const float*)d_in[14];
  const float* w2 = (const float*)d_in[15];
  const float* b2 = (const float*)d_in[16];
  float* out = (float*)d_out;

  char* ws = (char*)d_ws;
  const size_t MB = 1024 * 1024;
  __bf16* wqkv_t = (__bf16*)(ws + 0 * MB);
  __bf16* wq_t = (__bf16*)(ws + 0 * MB);
  __bf16* wk_t = (__bf16*)(ws + 2 * MB);
  __bf16* wv_t = (__bf16*)(ws + 4 * MB);
  __bf16* wo_t = (__bf16*)(ws + 6 * MB);
  __bf16* w1_t = (__bf16*)(ws + 8 * MB);
  __bf16* w2_t = (__bf16*)(ws + 16 * MB);
  __bf16* hbuf = (__bf16*)(ws + 24 * MB);
  __bf16* qbuf = (__bf16*)(ws + 40 * MB);
  __bf16* kbuf = (__bf16*)(ws + 56 * MB);
  __bf16* vtbuf = (__bf16*)(ws + 72 * MB);
  __bf16* ctxbuf = (__bf16*)(ws + 88 * MB);
  __bf16* ff1 = (__bf16*)(ws + 40 * MB);

  dim3 tb(32, 8);
  transpose_w<<<dim3(32, 32), tb, 0, stream>>>(wq, wq_t, 1024, 1024);
  transpose_w<<<dim3(32, 32), tb, 0, stream>>>(wk, wk_t, 1024, 1024);
  transpose_w<<<dim3(32, 32), tb, 0, stream>>>(wv, wv_t, 1024, 1024);
  transpose_w<<<dim3(32, 32), tb, 0, stream>>>(wo, wo_t, 1024, 1024);
  transpose_w<<<dim3(128, 32), tb, 0, stream>>>(w1, w1_t, 1024, 4096);
  transpose_w<<<dim3(32, 128), tb, 0, stream>>>(w2, w2_t, 4096, 1024);

  ln_kernel<<<8192, 256, 0, stream>>>(x, ln1w, ln1b, hbuf);

  gemm256<MODE_QKV><<<dim3(12, 32), 512, 0, stream>>>(
      hbuf, wqkv_t, bq, bk, bv, nullptr, qbuf, kbuf, vtbuf, 3072, 1024);

  attn_kernel<<<dim3(128, 8), 256, 0, stream>>>(qbuf, kbuf, vtbuf, ctxbuf);

  gemm_bt<MODE_WO><<<dim3(8, 64), 256, 0, stream>>>(
      ctxbuf, wo_t, bo, nullptr, nullptr, x, out, nullptr, nullptr, 1024, 1024);

  ln_kernel<<<8192, 256, 0, stream>>>(out, ln2w, ln2b, hbuf);

  gemm256<MODE_F1><<<dim3(16, 32), 512, 0, stream>>>(
      hbuf, w1_t, b1, nullptr, nullptr, nullptr, ff1, nullptr, nullptr, 4096, 1024);
  gemm_bt<MODE_F2><<<dim3(8, 64), 256, 0, stream>>>(
      ff1, w2_t, b2, nullptr, nullptr, out, out, nullptr, nullptr, 1024, 4096);
}

// Round 11
// 490.777 us; speedup vs baseline: 1.1111x; 1.1111x over previous
//
#include <hip/hip_runtime.h>
#include <hip/hip_bf16.h>
#include <math.h>

typedef __bf16 bf16x8 __attribute__((ext_vector_type(8)));
typedef __bf16 bf16x4 __attribute__((ext_vector_type(4)));
typedef float f32x4 __attribute__((ext_vector_type(4)));

typedef __attribute__((address_space(3))) unsigned int lds_u32_t;
typedef __attribute__((address_space(1))) const unsigned int glb_u32_t;

static __device__ __forceinline__ f32x4 mfma16(bf16x8 a, bf16x8 b, f32x4 c) {
  return __builtin_amdgcn_mfma_f32_16x16x32_bf16(a, b, c, 0, 0, 0);
}

static __device__ __forceinline__ float fast_exp2(float x) {
#if __has_builtin(__builtin_amdgcn_exp2f)
  return __builtin_amdgcn_exp2f(x);
#else
  return exp2f(x);
#endif
}

static __device__ __forceinline__ float fast_rcp(float x) {
#if __has_builtin(__builtin_amdgcn_rcpf)
  return __builtin_amdgcn_rcpf(x);
#else
  return 1.f / x;
#endif
}

// GELU with A&S 7.1.26 erf (max abs err 1.5e-7 — far below bf16 quantum).
// R9 verified: VALUBusy 44% -> 11% on F1. Keep.
static __device__ __forceinline__ float fast_gelu(float x) {
  float z = x * 0.70710678118654752f;
  float az = fabsf(z);
  float t = fast_rcp(fmaf(0.3275911f, az, 1.f));
  float poly = t * fmaf(t, fmaf(t, fmaf(t, fmaf(t, 1.061405429f, -1.453152027f),
                                        1.421413741f), -0.284496736f), 0.254829592f);
  float e = fast_exp2(-az * az * 1.4426950408889634f);
  float erf_abs = fmaf(-poly, e, 1.f);
  float erfv = copysignf(erf_abs, z);
  return 0.5f * x * (1.f + erfv);
}

static __device__ __forceinline__ void load_lds16(const __bf16* g, __bf16* l) {
  __builtin_amdgcn_global_load_lds((glb_u32_t*)g, (lds_u32_t*)l, 16, 0, 0);
}

// ---------------- weight transpose: src[R][C] fp32 -> dst[C][R] bf16 ----------------
__global__ __launch_bounds__(256) void transpose_w(const float* __restrict__ src,
                                                   __bf16* __restrict__ dst,
                                                   int R, int C) {
  __shared__ float tile[32][33];
  int tx = threadIdx.x, ty = threadIdx.y;
  int c0 = blockIdx.x * 32, r0 = blockIdx.y * 32;
#pragma unroll
  for (int i = 0; i < 4; i++)
    tile[ty + 8 * i][tx] = src[(size_t)(r0 + ty + 8 * i) * C + c0 + tx];
  __syncthreads();
#pragma unroll
  for (int i = 0; i < 4; i++)
    dst[(size_t)(c0 + ty + 8 * i) * R + r0 + tx] = (__bf16)tile[tx][ty + 8 * i];
}

// ---------------- layernorm (row=1024) fp32 in -> bf16 out ----------------
__global__ __launch_bounds__(256) void ln_kernel(const float* __restrict__ x,
                                                 const float* __restrict__ w,
                                                 const float* __restrict__ b,
                                                 __bf16* __restrict__ out) {
  int row = blockIdx.x, tid = threadIdx.x;
  const float* xr = x + (size_t)row * 1024;
  float v[4];
  float s = 0.f, sq = 0.f;
#pragma unroll
  for (int i = 0; i < 4; i++) {
    v[i] = xr[tid + 256 * i];
    s += v[i];
    sq += v[i] * v[i];
  }
#pragma unroll
  for (int off = 1; off < 64; off <<= 1) {
    s += __shfl_xor(s, off, 64);
    sq += __shfl_xor(sq, off, 64);
  }
  __shared__ float red[8];
  int wave = tid >> 6, lane = tid & 63;
  if (lane == 0) { red[wave] = s; red[4 + wave] = sq; }
  __syncthreads();
  if (tid == 0) {
    float S = red[0] + red[1] + red[2] + red[3];
    float SQ = red[4] + red[5] + red[6] + red[7];
    float mu = S * (1.f / 1024.f);
    float var = SQ * (1.f / 1024.f) - mu * mu;
    red[0] = mu;
    red[1] = rsqrtf(var + 1e-5f);
  }
  __syncthreads();
  float mu = red[0], rstd = red[1];
  __bf16* orow = out + (size_t)row * 1024;
#pragma unroll
  for (int i = 0; i < 4; i++) {
    int c = tid + 256 * i;
    orow[c] = (__bf16)((v[i] - mu) * rstd * w[c] + b[c]);
  }
}

// ---------------- GEMM modes ----------------
enum { MODE_QKV = 0, MODE_WO = 3, MODE_F1 = 4, MODE_F2 = 5 };

// ---------------- 128x128 GEMM (m97-structure) — kept for WO / F2 ----------------
template <int MODE>
__global__ __launch_bounds__(256, 2) void gemm_bt(const __bf16* __restrict__ A,
                                                  const __bf16* __restrict__ Bt,
                                                  const float* __restrict__ b0,
                                                  const float* __restrict__ b1,
                                                  const float* __restrict__ b2,
                                                  const float* __restrict__ aux,
                                                  void* __restrict__ o0,
                                                  void* __restrict__ o1,
                                                  void* __restrict__ o2,
                                                  int N, int K) {
  __shared__ __align__(16) __bf16 As[128 * 64];
  __shared__ __align__(16) __bf16 Bs[128 * 64];
  const int tid = threadIdx.x;
  const int m0 = blockIdx.y * 128, n0 = blockIdx.x * 128;
  const int wave = tid >> 6, lane = tid & 63, quad = lane >> 4, l16 = lane & 15;
  const int wm = (wave >> 1) * 64, wn = (wave & 1) * 64;

  int srow[4], sgran[4];
#pragma unroll
  for (int i = 0; i < 4; i++) {
    int inst = wave * 4 + i;
    srow[i] = inst * 8 + (lane >> 3);
    sgran[i] = (lane & 7) ^ (srow[i] & 7);
  }

  const f32x4 zero4 = {0.f, 0.f, 0.f, 0.f};
  f32x4 acc[4][4];
#pragma unroll
  for (int i = 0; i < 4; i++)
#pragma unroll
    for (int j = 0; j < 4; j++) acc[i][j] = zero4;

  for (int kt = 0; kt < K; kt += 64) {
#pragma unroll
    for (int i = 0; i < 4; i++) {
      int inst = wave * 4 + i;
      load_lds16(&A[(size_t)(m0 + srow[i]) * K + kt + sgran[i] * 8], &As[inst * 512]);
      load_lds16(&Bt[(size_t)(n0 + srow[i]) * K + kt + sgran[i] * 8], &Bs[inst * 512]);
    }
    __syncthreads();
#pragma unroll
    for (int ks = 0; ks < 64; ks += 32) {
      bf16x8 af[4], bfv[4];
#pragma unroll
      for (int mi = 0; mi < 4; mi++) {
        int row = wm + 16 * mi + l16;
        int pg = ((ks >> 3) + quad) ^ (row & 7);
        af[mi] = *(const bf16x8*)&As[row * 64 + pg * 8];
      }
#pragma unroll
      for (int ni = 0; ni < 4; ni++) {
        int row = wn + 16 * ni + l16;
        int pg = ((ks >> 3) + quad) ^ (row & 7);
        bfv[ni] = *(const bf16x8*)&Bs[row * 64 + pg * 8];
      }
#pragma unroll
      for (int mi = 0; mi < 4; mi++)
#pragma unroll
        for (int ni = 0; ni < 4; ni++)
          acc[mi][ni] = mfma16(af[mi], bfv[ni], acc[mi][ni]);
    }
    __syncthreads();
  }

  int seg = (n0 >> 10);
  const float* bsel = (MODE == MODE_QKV) ? (seg == 0 ? b0 : seg == 1 ? b1 : b2) : b0;

#pragma unroll
  for (int mi = 0; mi < 4; mi++) {
#pragma unroll
    for (int ni = 0; ni < 4; ni++) {
      int ncol = n0 + wn + 16 * ni + l16;
      int cc = ncol & 1023;
      float bval = bsel[(MODE == MODE_QKV) ? cc : ncol];
#pragma unroll
      for (int r = 0; r < 4; r++) {
        int m = m0 + wm + 16 * mi + quad * 4 + r;
        float val = acc[mi][ni][r] + bval;
        if constexpr (MODE == MODE_QKV) {
          int bb = m >> 10, s = m & 1023, h = cc >> 6, dk = cc & 63;
          if (seg == 0)
            ((__bf16*)o0)[(((size_t)(bb * 16 + h)) * 1024 + s) * 64 + dk] =
                (__bf16)(val * 0.18033688011112042f);
          else if (seg == 1)
            ((__bf16*)o1)[(((size_t)(bb * 16 + h)) * 1024 + s) * 64 + dk] = (__bf16)val;
          else
            ((__bf16*)o2)[(((size_t)(bb * 16 + h)) * 64 + dk) * 1024 + s] = (__bf16)val;
        } else if constexpr (MODE == MODE_WO) {
          val = fmaxf(val, 0.f);
          size_t idx = (size_t)m * 1024 + ncol;
          ((float*)o0)[idx] = aux[idx] + val;
        } else if constexpr (MODE == MODE_F1) {
          ((__bf16*)o0)[(size_t)m * 4096 + ncol] = (__bf16)fast_gelu(val);
        } else {
          size_t idx = (size_t)m * 1024 + ncol;
          ((float*)o0)[idx] = aux[idx] + val;
        }
      }
    }
  }
}

// ---------------- 256x256 GEMM v3: row-major+slot-XOR LDS, ring-4, counted vmcnt ---
// R7 (v1 pair-interleave): conflicts 6.29M, 105us. R9 (v2 [g][row] panels):
// conflicts 0 BUT staging touched 64 lines/instr (lane=row, stride K) -> VMEM
// line-processing bound, 124us, MfmaUtil 16%. v3 combines the halves that worked:
//   LDS byte(r,q) = r*64 + slot*16, slot = q ^ ((r>>1)&3)   (q = k-octet 0..3)
// STAGING (v1-class coalescing): instr = 16 rows x 64B line each (4 lanes/row
//   cover the row's whole 32-elem K-tile, granule-permuted within the line);
//   lane l -> row r0+(l>>2), src granule (l&3)^((l>>3)&3); r0 mult of 16 so the
//   write-side mapping identically matches the read formula. 16 lines/instr.
// READS (v2-class conflict-free): bank-group (byte>>4)&7 = 4(r&1) + q^((r>>1)&3)
//   is bijective over 8 groups per 8 consecutive rows -> 16 lanes = 2/group =
//   free 2-way floor; a full-wave b128 read covers 16 complete rows, each 16B
//   granule exactly once. Per-lane slot = quad ^ ((l16>>1)&3); offs = base+mi*1024.
// 4 issues/wave/stage -> R7-verified vmcnt(8)/(4)/(0) ring unchanged.
template <int MODE>
__global__ __launch_bounds__(512, 2) void gemm256(const __bf16* __restrict__ A,
                                                  const __bf16* __restrict__ Bt,
                                                  const float* __restrict__ b0,
                                                  const float* __restrict__ b1,
                                                  const float* __restrict__ b2,
                                                  const float* __restrict__ aux,
                                                  void* __restrict__ o0,
                                                  void* __restrict__ o1,
                                                  void* __restrict__ o2,
                                                  int N, int K) {
  __shared__ __align__(16) __bf16 As[4][8192];  // slot: 256 rows x 32k, row-major+XOR
  __shared__ __align__(16) __bf16 Bs[4][8192];
  const int tid = threadIdx.x;
  const int m0 = blockIdx.y * 256, n0 = blockIdx.x * 256;
  const int wave = tid >> 6, lane = tid & 63, quad = lane >> 4, l16 = lane & 15;
  const int wr = wave >> 2, wc = wave & 3;  // 2 x 4 wave grid; per-wave 128 x 64 output

  // staging: lane l -> row (wave&3)*64 + (l>>2), source granule (l&3)^((l>>3)&3)
  const int srowL = lane >> 2;
  const int sq = (lane & 3) ^ ((lane >> 3) & 3);
  const __bf16* pS = (wave < 4)
                         ? A + (size_t)(m0 + (wave & 3) * 64 + srowL) * K + 8 * sq
                         : Bt + (size_t)(n0 + (wave & 3) * 64 + srowL) * K + 8 * sq;
  const int dstoff = (wave & 3) * 2048;  // elements: row (wave&3)*64 at byte r*64

  // fragment read offsets (bytes): row r, granule quad -> r*64 + (quad^((r>>1)&3))*16
  const int slotL = quad ^ ((l16 >> 1) & 3);
  const int abase = (wr * 128 + l16) * 64 + slotL * 16;
  const int bbase = (wc * 64 + l16) * 64 + slotL * 16;

  const f32x4 zero4 = {0.f, 0.f, 0.f, 0.f};
  f32x4 acc[8][4];
#pragma unroll
  for (int i = 0; i < 8; i++)
#pragma unroll
    for (int j = 0; j < 4; j++) acc[i][j] = zero4;

  const int nt = K >> 5;

  auto stage = [&](int t) {
    __bf16* b = ((wave < 4) ? &As[t & 3][0] : &Bs[t & 3][0]) + dstoff;
#pragma unroll
    for (int i = 0; i < 4; i++) load_lds16(pS + (size_t)(16 * i) * K, b + 512 * i);
    pS += 32;
  };

  auto window = [&](int t, bool dostage) {
    const char* ab = (const char*)&As[t & 3][0];
    const char* bb = (const char*)&Bs[t & 3][0];
    bf16x8 af[8], bfv[4];
#pragma unroll
    for (int mi = 0; mi < 8; mi++) af[mi] = *(const bf16x8*)(ab + abase + mi * 1024);
#pragma unroll
    for (int nj = 0; nj < 4; nj++) bfv[nj] = *(const bf16x8*)(bb + bbase + nj * 1024);
    if (dostage) stage(t + 3);
    __builtin_amdgcn_s_setprio(1);
#pragma unroll
    for (int mi = 0; mi < 8; mi++)
#pragma unroll
      for (int nj = 0; nj < 4; nj++)
        acc[mi][nj] = mfma16(af[mi], bfv[nj], acc[mi][nj]);
    __builtin_amdgcn_s_setprio(0);
  };

  // prologue: 3 tiles in flight, wait for tile 0 only
  stage(0);
  stage(1);
  stage(2);
  asm volatile("s_waitcnt vmcnt(8)" ::: "memory");
  __builtin_amdgcn_s_barrier();
  __builtin_amdgcn_sched_barrier(0);

  for (int t = 0; t < nt - 3; ++t) {
    window(t, true);
    asm volatile("s_waitcnt vmcnt(8)" ::: "memory");
    __builtin_amdgcn_s_barrier();
    __builtin_amdgcn_sched_barrier(0);
  }
  window(nt - 3, false);
  asm volatile("s_waitcnt vmcnt(4)" ::: "memory");
  __builtin_amdgcn_s_barrier();
  __builtin_amdgcn_sched_barrier(0);
  window(nt - 2, false);
  asm volatile("s_waitcnt vmcnt(0)" ::: "memory");
  __builtin_amdgcn_s_barrier();
  __builtin_amdgcn_sched_barrier(0);
  window(nt - 1, false);

  // ---- epilogue (frag layout: col=l16, row=4*quad+r)
  int seg = (n0 >> 10);
  const float* bsel = (MODE == MODE_QKV) ? (seg == 0 ? b0 : seg == 1 ? b1 : b2) : b0;

#pragma unroll
  for (int mi = 0; mi < 8; mi++) {
#pragma unroll
    for (int nj = 0; nj < 4; nj++) {
      int ncol = n0 + wc * 64 + 16 * nj + l16;
      int cc = ncol & 1023;
      float bval = bsel[(MODE == MODE_QKV) ? cc : ncol];
#pragma unroll
      for (int r = 0; r < 4; r++) {
        int m = m0 + wr * 128 + 16 * mi + quad * 4 + r;
        float val = acc[mi][nj][r] + bval;
        if constexpr (MODE == MODE_QKV) {
          int bb = m >> 10, s = m & 1023, h = cc >> 6, dk = cc & 63;
          if (seg == 0)  // fold 1/sqrt(64) * log2(e) so attn uses raw exp2
            ((__bf16*)o0)[(((size_t)(bb * 16 + h)) * 1024 + s) * 64 + dk] =
                (__bf16)(val * 0.18033688011112042f);
          else if (seg == 1)
            ((__bf16*)o1)[(((size_t)(bb * 16 + h)) * 1024 + s) * 64 + dk] = (__bf16)val;
          else
            ((__bf16*)o2)[(((size_t)(bb * 16 + h)) * 64 + dk) * 1024 + s] = (__bf16)val;
        } else if constexpr (MODE == MODE_WO) {
          val = fmaxf(val, 0.f);
          size_t idx = (size_t)m * 1024 + ncol;
          ((float*)o0)[idx] = aux[idx] + val;
        } else if constexpr (MODE == MODE_F1) {
          ((__bf16*)o0)[(size_t)m * 4096 + ncol] = (__bf16)fast_gelu(val);
        } else {
          size_t idx = (size_t)m * 1024 + ncol;
          ((float*)o0)[idx] = aux[idx] + val;
        }
      }
    }
  }
}

// ---------------- flash attention v7: LDS-shared K/V tiles (unchanged, verified R7)
__global__ __launch_bounds__(256, 2) void attn_kernel(const __bf16* __restrict__ Q,
                                                      const __bf16* __restrict__ Kp,
                                                      const __bf16* __restrict__ Vt,
                                                      __bf16* __restrict__ ctx) {
  __shared__ __align__(16) __bf16 Ks[2][64][64];
  __shared__ __align__(16) __bf16 Vs[2][64][64];
  __shared__ __align__(16) __bf16 Ps[2][4][32][72];
  const int tid = threadIdx.x;
  const int bh = blockIdx.x, qb = blockIdx.y;
  const int wave = tid >> 6, lane = tid & 63, quad = lane >> 4, l16 = lane & 15;
  const int qrow0 = qb * 128 + wave * 32;

  bf16x8 aq[2][2];
#pragma unroll
  for (int mi = 0; mi < 2; mi++) {
    const __bf16* qrow = Q + ((size_t)bh * 1024 + qrow0 + mi * 16 + l16) * 64;
    aq[mi][0] = *(const bf16x8*)&qrow[8 * quad];
    aq[mi][1] = *(const bf16x8*)&qrow[32 + 8 * quad];
  }

  const f32x4 zero4 = {0.f, 0.f, 0.f, 0.f};
  f32x4 o[2][4];
  float lp[2] = {0.f, 0.f};
#pragma unroll
  for (int mi = 0; mi < 2; mi++)
#pragma unroll
    for (int nj = 0; nj < 4; nj++) o[mi][nj] = zero4;

  const __bf16* kb0 = Kp + (size_t)bh * 65536;
  const __bf16* vb0 = Vt + (size_t)bh * 65536;

  const int srow = lane >> 3;
  const int sgran = (lane & 7) ^ srow;
  const int r0 = wave * 16;

  auto stage = [&](int t) {
    int buf = t & 1;
    const __bf16* ks = kb0 + (size_t)(t * 64 + r0 + srow) * 64 + sgran * 8;
    load_lds16(ks, &Ks[buf][r0][0]);
    load_lds16(ks + 8 * 64, &Ks[buf][r0 + 8][0]);
    const __bf16* vs = vb0 + (size_t)(r0 + srow) * 1024 + t * 64 + sgran * 8;
    load_lds16(vs, &Vs[buf][r0][0]);
    load_lds16(vs + 8 * 1024, &Vs[buf][r0 + 8][0]);
  };

  int kOff[4][2], vOff[4][2];
#pragma unroll
  for (int ni = 0; ni < 4; ni++) {
    int r = 16 * ni + l16;
#pragma unroll
    for (int half = 0; half < 2; half++) {
      int g = quad + 4 * half;
      kOff[ni][half] = r * 128 + ((g ^ (r & 7)) * 16);
      vOff[ni][half] = kOff[ni][half];
    }
  }

  stage(0);
  asm volatile("s_waitcnt vmcnt(0)" ::: "memory");
  __builtin_amdgcn_s_barrier();

  for (int t = 0; t < 16; ++t) {
    const int buf = t & 1;
    if (t < 15) stage(t + 1);
    const char* kbuf_ = (const char*)&Ks[buf][0][0];
    const char* vbuf_ = (const char*)&Vs[buf][0][0];
    bf16x8 kf[4][2];
#pragma unroll
    for (int ni = 0; ni < 4; ni++) {
      kf[ni][0] = *(const bf16x8*)(kbuf_ + kOff[ni][0]);
      kf[ni][1] = *(const bf16x8*)(kbuf_ + kOff[ni][1]);
    }
    f32x4 st[2][4];
    __builtin_amdgcn_s_setprio(1);
#pragma unroll
    for (int mi = 0; mi < 2; mi++)
#pragma unroll
      for (int ni = 0; ni < 4; ni++) {
        st[mi][ni] = mfma16(kf[ni][0], aq[mi][0], zero4);
        st[mi][ni] = mfma16(kf[ni][1], aq[mi][1], st[mi][ni]);
      }
    __builtin_amdgcn_s_setprio(0);
    bf16x8 vf[2][4];
#pragma unroll
    for (int nj = 0; nj < 4; nj++) {
      vf[0][nj] = *(const bf16x8*)(vbuf_ + vOff[nj][0]);
      vf[1][nj] = *(const bf16x8*)(vbuf_ + vOff[nj][1]);
    }
#pragma unroll
    for (int mi = 0; mi < 2; mi++)
#pragma unroll
      for (int ni = 0; ni < 4; ni++) {
        union { bf16x4 v4; __bf16 b[4]; } pk;
#pragma unroll
        for (int r = 0; r < 4; r++) {
          float p = fast_exp2(st[mi][ni][r]);
          lp[mi] += p;
          pk.b[r] = (__bf16)p;
        }
        *(bf16x4*)&Ps[buf][wave][16 * mi + l16][16 * ni + 4 * quad] = pk.v4;
      }
    bf16x8 pa[2][2];
#pragma unroll
    for (int mi = 0; mi < 2; mi++) {
      pa[mi][0] = *(const bf16x8*)&Ps[buf][wave][16 * mi + l16][8 * quad];
      pa[mi][1] = *(const bf16x8*)&Ps[buf][wave][16 * mi + l16][32 + 8 * quad];
    }
    __builtin_amdgcn_s_setprio(1);
#pragma unroll
    for (int mi = 0; mi < 2; mi++)
#pragma unroll
      for (int nj = 0; nj < 4; nj++) {
        o[mi][nj] = mfma16(pa[mi][0], vf[0][nj], o[mi][nj]);
        o[mi][nj] = mfma16(pa[mi][1], vf[1][nj], o[mi][nj]);
      }
    __builtin_amdgcn_s_setprio(0);
    if (t < 15) {
      asm volatile("s_waitcnt vmcnt(0)" ::: "memory");
      __builtin_amdgcn_s_barrier();
    }
  }

#pragma unroll
  for (int mi = 0; mi < 2; mi++) {
    lp[mi] += __shfl_xor(lp[mi], 16, 64);
    lp[mi] += __shfl_xor(lp[mi], 32, 64);
  }

  int bb = bh >> 4, h = bh & 15;
#pragma unroll
  for (int mi = 0; mi < 2; mi++)
#pragma unroll
    for (int r = 0; r < 4; r++) {
      float inv = 1.f / __shfl(lp[mi], 4 * quad + r, 64);
      int s = qrow0 + mi * 16 + 4 * quad + r;
#pragma unroll
      for (int nj = 0; nj < 4; nj++)
        ctx[((size_t)(bb * 1024 + s)) * 1024 + h * 64 + nj * 16 + l16] =
            (__bf16)(o[mi][nj][r] * inv);
    }
}

// ---------------- launch ----------------
extern "C" void kernel_launch(void* const* d_in, const int* in_sizes, int n_in,
                              void* d_out, int out_size, void* d_ws, size_t ws_size,
                              hipStream_t stream) {
  const float* x = (const float*)d_in[0];
  const float* ln1w = (const float*)d_in[1];
  const float* ln1b = (const float*)d_in[2];
  const float* wq = (const float*)d_in[3];
  const float* bq = (const float*)d_in[4];
  const float* wk = (const float*)d_in[5];
  const float* bk = (const float*)d_in[6];
  const float* wv = (const float*)d_in[7];
  const float* bv = (const float*)d_in[8];
  const float* wo = (const float*)d_in[9];
  const float* bo = (const float*)d_in[10];
  const float* ln2w = (const float*)d_in[11];
  const float* ln2b = (const float*)d_in[12];
  const float* w1 = (const float*)d_in[13];
  const float* b1 = (const float*)d_in[14];
  const float* w2 = (const float*)d_in[15];
  const float* b2 = (const float*)d_in[16];
  float* out = (float*)d_out;

  char* ws = (char*)d_ws;
  const size_t MB = 1024 * 1024;
  __bf16* wqkv_t = (__bf16*)(ws + 0 * MB);
  __bf16* wq_t = (__bf16*)(ws + 0 * MB);
  __bf16* wk_t = (__bf16*)(ws + 2 * MB);
  __bf16* wv_t = (__bf16*)(ws + 4 * MB);
  __bf16* wo_t = (__bf16*)(ws + 6 * MB);
  __bf16* w1_t = (__bf16*)(ws + 8 * MB);
  __bf16* w2_t = (__bf16*)(ws + 16 * MB);
  __bf16* hbuf = (__bf16*)(ws + 24 * MB);
  __bf16* qbuf = (__bf16*)(ws + 40 * MB);
  __bf16* kbuf = (__bf16*)(ws + 56 * MB);
  __bf16* vtbuf = (__bf16*)(ws + 72 * MB);
  __bf16* ctxbuf = (__bf16*)(ws + 88 * MB);
  __bf16* ff1 = (__bf16*)(ws + 40 * MB);

  dim3 tb(32, 8);
  transpose_w<<<dim3(32, 32), tb, 0, stream>>>(wq, wq_t, 1024, 1024);
  transpose_w<<<dim3(32, 32), tb, 0, stream>>>(wk, wk_t, 1024, 1024);
  transpose_w<<<dim3(32, 32), tb, 0, stream>>>(wv, wv_t, 1024, 1024);
  transpose_w<<<dim3(32, 32), tb, 0, stream>>>(wo, wo_t, 1024, 1024);
  transpose_w<<<dim3(128, 32), tb, 0, stream>>>(w1, w1_t, 1024, 4096);
  transpose_w<<<dim3(32, 128), tb, 0, stream>>>(w2, w2_t, 4096, 1024);

  ln_kernel<<<8192, 256, 0, stream>>>(x, ln1w, ln1b, hbuf);

  gemm256<MODE_QKV><<<dim3(12, 32), 512, 0, stream>>>(
      hbuf, wqkv_t, bq, bk, bv, nullptr, qbuf, kbuf, vtbuf, 3072, 1024);

  attn_kernel<<<dim3(128, 8), 256, 0, stream>>>(qbuf, kbuf, vtbuf, ctxbuf);

  gemm_bt<MODE_WO><<<dim3(8, 64), 256, 0, stream>>>(
      ctxbuf, wo_t, bo, nullptr, nullptr, x, out, nullptr, nullptr, 1024, 1024);

  ln_kernel<<<8192, 256, 0, stream>>>(out, ln2w, ln2b, hbuf);

  gemm256<MODE_F1><<<dim3(16, 32), 512, 0, stream>>>(
      hbuf, w1_t, b1, nullptr, nullptr, nullptr, ff1, nullptr, nullptr, 4096, 1024);
  gemm_bt<MODE_F2><<<dim3(8, 64), 256, 0, stream>>>(
      ff1, w2_t, b2, nullptr, nullptr, out, out, nullptr, nullptr, 1024, 4096);
}